// Round 9
// baseline (507.704 us; speedup 1.0000x reference)
//
#include <hip/hip_runtime.h>
#include <hip/hip_bf16.h>

typedef unsigned short ushort_t;
typedef float f32x4 __attribute__((ext_vector_type(4)));
typedef __bf16 bf16x8 __attribute__((ext_vector_type(8)));

typedef const __attribute__((address_space(1))) void* gptr_t;
typedef __attribute__((address_space(3))) void* sptr_t;

#define GLD16(g, l) __builtin_amdgcn_global_load_lds((gptr_t)(g), (sptr_t)(l), 16, 0, 0)

// ---------------------------------------------------------------------------
// Kernel 1: global sum of W (fp32 partials, double atomic) -> ws scalar
// ---------------------------------------------------------------------------
__global__ void sum_w_kernel(const float* __restrict__ W, double* __restrict__ out, int n4) {
    int i = blockIdx.x * blockDim.x + threadIdx.x;
    int stride = gridDim.x * blockDim.x;
    float s = 0.f;
    for (; i < n4; i += stride) {
        float4 v = ((const float4*)W)[i];
        s += (v.x + v.y) + (v.z + v.w);
    }
    #pragma unroll
    for (int off = 32; off > 0; off >>= 1) s += __shfl_down(s, off, 64);
    __shared__ float red[4];
    int t = threadIdx.x;
    if ((t & 63) == 0) red[t >> 6] = s;
    __syncthreads();
    if (t == 0) {
        float bs = red[0] + red[1] + red[2] + red[3];
        atomicAdd(out, (double)bs);
    }
}

// ---------------------------------------------------------------------------
// Kernel 2: quantize W -> bf16 {0,1}
// ---------------------------------------------------------------------------
__global__ void quant_w_kernel(const float* __restrict__ W, ushort_t* __restrict__ Wq,
                               const double* __restrict__ sumw, float inv_n, int n4) {
    float mean = (float)(*sumw) * inv_n;
    int i = blockIdx.x * blockDim.x + threadIdx.x;
    int stride = gridDim.x * blockDim.x;
    for (; i < n4; i += stride) {
        float4 v = ((const float4*)W)[i];
        ushort4 o;
        o.x = (v.x > mean) ? 0x3F80 : 0;
        o.y = (v.y > mean) ? 0x3F80 : 0;
        o.z = (v.z > mean) ? 0x3F80 : 0;
        o.w = (v.w > mean) ? 0x3F80 : 0;
        ((ushort4*)Wq)[i] = o;
    }
}

// ---------------------------------------------------------------------------
// Kernel 3: convert x -> bf16 (round-to-nearest)
// ---------------------------------------------------------------------------
__device__ __forceinline__ ushort_t f2bf(float f) {
    __hip_bfloat16 h = __float2bfloat16(f);
    return *(ushort_t*)&h;
}

__global__ void cvt_x_kernel(const float* __restrict__ x, ushort_t* __restrict__ xb, int n4) {
    int i = blockIdx.x * blockDim.x + threadIdx.x;
    int stride = gridDim.x * blockDim.x;
    for (; i < n4; i += stride) {
        float4 v = ((const float4*)x)[i];
        ushort4 o;
        o.x = f2bf(v.x);
        o.y = f2bf(v.y);
        o.z = f2bf(v.z);
        o.w = f2bf(v.w);
        ((ushort4*)xb)[i] = o;
    }
}

// ---------------------------------------------------------------------------
// Kernel 4: quantize b (single block; n = 4096)
// ---------------------------------------------------------------------------
__global__ void quant_b_kernel(const float* __restrict__ b, float* __restrict__ bq, int n) {
    int t = threadIdx.x;
    float s = 0.f;
    for (int i = t; i < n; i += 256) s += b[i];
    #pragma unroll
    for (int off = 32; off > 0; off >>= 1) s += __shfl_down(s, off, 64);
    __shared__ float red[4];
    if ((t & 63) == 0) red[t >> 6] = s;
    __syncthreads();
    float mean = (red[0] + red[1] + red[2] + red[3]) / (float)n;
    for (int i = t; i < n; i += 256) bq[i] = (b[i] > mean) ? 1.0f : 0.0f;
}

// ---------------------------------------------------------------------------
// Kernel 5: bf16 MFMA GEMM, 256x256 tile, BK=64, 8 waves (2Mx4N).
// SINGLE-BARRIER tile + counted-lgkm READ PIPELINING (reads stay in buf P):
//   ph1: 8 stages->PN; 16 ds_reads (a0:8,b0:4,b1:4); lgkm(4) [forces a0,b0,
//        leaves b1 in flight]; MFMA Q00.
//   ph2: 8 ds_reads (a1); lgkm(8) [forces b1, issued one MFMA-region ago ->
//        drain covered]; MFMA Q01.
//   ph3: lgkm(0) [forces a1, covered]; MFMA Q11; MFMA Q10.
//   end: vmcnt(0) [all 8 stages ~3 phases old -> free] + ONE BAR.
// Waves free-skew within the tile, so one wave's ds_read drain overlaps other
// waves' MFMA (this was serialized in R4/R6/R8's 4-6-barrier lockstep).
// Safety: each wave's P-reads retired by its own ph3 lgkm(0) BEFORE the
// barrier -> t+1 stages into P cannot overwrite live reads; publication =
// per-wave vmcnt drain + BAR; compiler auto-waitcnt keeps operand correctness
// even if it reorders read issue (manual lgkm are scheduling, not safety).
//   C[M,N] = A[M,K] * B[N,K]^T
// LDS swizzle (full-granule): byte ^= ((byte>>3) & 0x70). Involution,
// row-preserving; 8 lanes/16B-granule = wave64 b128 floor (0 conflicts, R3).
// ---------------------------------------------------------------------------
#define PRIO1 __builtin_amdgcn_s_setprio(1)
#define PRIO0 __builtin_amdgcn_s_setprio(0)
#define BAR() __builtin_amdgcn_s_barrier()
#define WAITV0() asm volatile("s_waitcnt vmcnt(0)" ::: "memory")
#define LGKM_(n) asm volatile("s_waitcnt lgkmcnt(" #n ")" ::: "memory")
#define LGKMC(n) do { LGKM_(n); __builtin_amdgcn_sched_barrier(0); } while (0)
#define UNRL _Pragma("unroll")

__global__ __launch_bounds__(512, 2) void gemm_bf16_256(
        const ushort_t* __restrict__ A, const ushort_t* __restrict__ B,
        float* __restrict__ C, int M, int N, int K) {
    __shared__ ushort_t lds8[65536];   // 128 KiB: [buf][A 16K ushorts | B 16K ushorts]
    char* ldsc = (char*)lds8;

    int nbn = N >> 8;
    int nwg = gridDim.x;
    int bid = blockIdx.x;
    int cpx = nwg >> 3;
    int wg = (bid & 7) * cpx + (bid >> 3);   // XCD swizzle (nwg % 8 == 0)
    int tm = wg / nbn, tn = wg % nbn;

    int t = threadIdx.x;
    int w = t >> 6, l = t & 63;
    int wr = w >> 2, wc = w & 3;             // 2 M-waves x 4 N-waves
    int wrOff = wr * 8192;                   // 64 rows * 128 B
    int wcOff = wc * 4096;                   // 32 rows * 128 B

    // read-side lane offsets, full-granule swizzle folded in
    int baseL = ((l & 15) * 128) + ((l >> 4) * 16);
    int laneA0 = baseL ^ ((l & 7) << 4);     // K elems 0..31
    int laneA1 = laneA0 ^ 64;                // K elems 32..63 (bit6 flip pre-swz)

    // stage-side source offsets (inverse swizzle = same involution), 32-bit
    int offA[2][2], offB[2][2];
    UNRL
    for (int c = 0; c < 2; ++c) {
        int o = (t + c * 512) * 16;
        int os = o ^ ((o >> 3) & 0x70);
        int lr = os >> 7;
        int col = (os & 127) >> 1;
        UNRL
        for (int h = 0; h < 2; ++h) {
            offA[c][h] = ((lr >> 6) * 128 + h * 64 + (lr & 63)) * K + col;
            offB[c][h] = ((lr >> 5) * 64 + h * 32 + (lr & 31)) * K + col;
        }
    }

    const ushort_t* srcA = A + (size_t)tm * 256 * K;
    const ushort_t* srcB = B + (size_t)tn * 256 * K;

    f32x4 acc[8][4] = {};
    bf16x8 a0[4][2], a1[4][2], bf0[2][2], bf1[2][2];

#define STAGE_A(P, H, KIDX) do { \
    GLD16(srcA + (size_t)offA[0][H] + (KIDX), ldsc + (P)*65536 + (H)*16384 + w*1024); \
    GLD16(srcA + (size_t)offA[1][H] + (KIDX), ldsc + (P)*65536 + (H)*16384 + 8192 + w*1024); \
} while (0)
#define STAGE_B(P, H, KIDX) do { \
    GLD16(srcB + (size_t)offB[0][H] + (KIDX), ldsc + (P)*65536 + 32768 + (H)*16384 + w*1024); \
    GLD16(srcB + (size_t)offB[1][H] + (KIDX), ldsc + (P)*65536 + 32768 + (H)*16384 + 8192 + w*1024); \
} while (0)
#define LOAD_A(AF, P, H) do { UNRL for (int f = 0; f < 4; ++f) { \
    AF[f][0] = *(const bf16x8*)(ldsc + (P)*65536 + (H)*16384 + wrOff + f*2048 + laneA0); \
    AF[f][1] = *(const bf16x8*)(ldsc + (P)*65536 + (H)*16384 + wrOff + f*2048 + laneA1); \
} } while (0)
#define LOAD_B(BF, P, H) do { UNRL for (int e = 0; e < 2; ++e) { \
    BF[e][0] = *(const bf16x8*)(ldsc + (P)*65536 + 32768 + (H)*16384 + wcOff + e*2048 + laneA0); \
    BF[e][1] = *(const bf16x8*)(ldsc + (P)*65536 + 32768 + (H)*16384 + wcOff + e*2048 + laneA1); \
} } while (0)
#define MFMA_Q(QM, QN, AF, BF) do { UNRL for (int f = 0; f < 4; ++f) UNRL for (int e = 0; e < 2; ++e) { \
    acc[(QM)*4+f][(QN)*2+e] = __builtin_amdgcn_mfma_f32_16x16x32_bf16(AF[f][0], BF[e][0], acc[(QM)*4+f][(QN)*2+e], 0, 0, 0); \
    acc[(QM)*4+f][(QN)*2+e] = __builtin_amdgcn_mfma_f32_16x16x32_bf16(AF[f][1], BF[e][1], acc[(QM)*4+f][(QN)*2+e], 0, 0, 0); \
} } while (0)

// Single-barrier pipelined tile (see header comment).
#define TILE(P, PN, KTN) do { \
    STAGE_A(PN, 0, KTN); STAGE_B(PN, 0, KTN); STAGE_B(PN, 1, KTN); STAGE_A(PN, 1, KTN); \
    LOAD_A(a0, P, 0); LOAD_B(bf0, P, 0); LOAD_B(bf1, P, 1); \
    LGKMC(4); PRIO1; MFMA_Q(0, 0, a0, bf0); PRIO0; \
    LOAD_A(a1, P, 1); \
    LGKMC(8); PRIO1; MFMA_Q(0, 1, a0, bf1); PRIO0; \
    LGKMC(0); PRIO1; MFMA_Q(1, 1, a1, bf1); MFMA_Q(1, 0, a1, bf0); PRIO0; \
    WAITV0(); BAR(); \
} while (0)

    // prologue: stage tile 0 into buf0, drain once (outside main loop)
    STAGE_A(0, 0, 0); STAGE_B(0, 0, 0); STAGE_B(0, 1, 0); STAGE_A(0, 1, 0);
    WAITV0();
    BAR();

    for (int kt = 0; kt < K; kt += 128) {
        int kn1 = kt + 64;
        int kn2 = (kt + 128 < K) ? kt + 128 : 0;   // wrap: redundant, never read
        TILE(0, 1, kn1);
        TILE(1, 0, kn2);
    }

    // epilogue: C/D layout col = lane&15, row = (lane>>4)*4 + r
    int crow0 = tm * 256 + wr * 128 + (l >> 4) * 4;
    int ccol0 = tn * 256 + wc * 64 + (l & 15);
    UNRL
    for (int fm = 0; fm < 8; ++fm)
        UNRL
        for (int fn = 0; fn < 4; ++fn)
            UNRL
            for (int r = 0; r < 4; ++r)
                C[(size_t)(crow0 + fm * 16 + r) * N + (ccol0 + fn * 16)] = acc[fm][fn][r];
}

// ---------------------------------------------------------------------------
// Kernel 6: per-row normalize in-place: z = (z + bq - mean) / (sqrt(var_ddof1) + eps)
// ---------------------------------------------------------------------------
__device__ __forceinline__ float block_sum_256(float v, float* red) {
    #pragma unroll
    for (int off = 32; off > 0; off >>= 1) v += __shfl_down(v, off, 64);
    int t = threadIdx.x;
    __syncthreads();
    if ((t & 63) == 0) red[t >> 6] = v;
    __syncthreads();
    return red[0] + red[1] + red[2] + red[3];
}

__global__ void rownorm_kernel(float* __restrict__ z, const float* __restrict__ bq, int N) {
    __shared__ float red[4];
    int row = blockIdx.x;
    float* zr = z + (size_t)row * N;
    int t = threadIdx.x;

    float4 v[4];
    float s = 0.f;
    #pragma unroll
    for (int j = 0; j < 4; ++j) {
        int idx = t + j * 256;
        float4 a = ((const float4*)zr)[idx];
        float4 bb = ((const float4*)bq)[idx];
        a.x += bb.x; a.y += bb.y; a.z += bb.z; a.w += bb.w;
        v[j] = a;
        s += (a.x + a.y) + (a.z + a.w);
    }
    float total = block_sum_256(s, red);
    float mean = total * (1.0f / 4096.0f);

    float q = 0.f;
    #pragma unroll
    for (int j = 0; j < 4; ++j) {
        float dx = v[j].x - mean, dy = v[j].y - mean, dz = v[j].z - mean, dw = v[j].w - mean;
        q += (dx * dx + dy * dy) + (dz * dz + dw * dw);
    }
    float qtot = block_sum_256(q, red);
    float var = qtot * (1.0f / 4095.0f);
    float inv = 1.0f / (sqrtf(var) + 1e-8f);

    #pragma unroll
    for (int j = 0; j < 4; ++j) {
        int idx = t + j * 256;
        float4 o;
        o.x = (v[j].x - mean) * inv;
        o.y = (v[j].y - mean) * inv;
        o.z = (v[j].z - mean) * inv;
        o.w = (v[j].w - mean) * inv;
        ((float4*)zr)[idx] = o;
    }
}

// ---------------------------------------------------------------------------
extern "C" void kernel_launch(void* const* d_in, const int* in_sizes, int n_in,
                              void* d_out, int out_size, void* d_ws, size_t ws_size,
                              hipStream_t stream) {
    const float* x = (const float*)d_in[0];
    const float* W = (const float*)d_in[1];
    const float* b = (const float*)d_in[2];
    float* out = (float*)d_out;

    const int N = in_sizes[2];            // 4096 (OUT)
    const int K = in_sizes[1] / N;        // 4096 (IN)
    const int M = in_sizes[0] / K;        // 8192

    // workspace layout
    char* ws = (char*)d_ws;
    ushort_t* xb = (ushort_t*)ws;                                   // M*K bf16
    ushort_t* wq = (ushort_t*)(ws + (size_t)M * K * 2);             // N*K bf16
    float* bq = (float*)(ws + (size_t)M * K * 2 + (size_t)N * K * 2);  // N fp32
    double* sumw = (double*)(ws + (size_t)M * K * 2 + (size_t)N * K * 2 + (size_t)N * 4);

    hipMemsetAsync(sumw, 0, sizeof(double), stream);
    sum_w_kernel<<<1024, 256, 0, stream>>>(W, sumw, N * K / 4);
    quant_w_kernel<<<2048, 256, 0, stream>>>(W, wq, sumw, 1.0f / (float)((size_t)N * K), N * K / 4);
    cvt_x_kernel<<<2048, 256, 0, stream>>>(x, xb, M * K / 4);
    quant_b_kernel<<<1, 256, 0, stream>>>(b, bq, N);

    int grid = (M / 256) * (N / 256);
    gemm_bf16_256<<<grid, 512, 0, stream>>>(xb, wq, out, M, N, K);

    rownorm_kernel<<<M, 256, 0, stream>>>(out, bq, N);
}

// Round 10
// 361.550 us; speedup vs baseline: 1.4042x; 1.4042x over previous
//
#include <hip/hip_runtime.h>
#include <hip/hip_bf16.h>

typedef unsigned short ushort_t;
typedef float f32x16 __attribute__((ext_vector_type(16)));
typedef __bf16 bf16x8 __attribute__((ext_vector_type(8)));

typedef const __attribute__((address_space(1))) void* gptr_t;
typedef __attribute__((address_space(3))) void* sptr_t;

#define GLD16(g, l) __builtin_amdgcn_global_load_lds((gptr_t)(g), (sptr_t)(l), 16, 0, 0)

// ---------------------------------------------------------------------------
// Kernel 1: global sum of W (fp32 partials, double atomic) -> ws scalar
// ---------------------------------------------------------------------------
__global__ void sum_w_kernel(const float* __restrict__ W, double* __restrict__ out, int n4) {
    int i = blockIdx.x * blockDim.x + threadIdx.x;
    int stride = gridDim.x * blockDim.x;
    float s = 0.f;
    for (; i < n4; i += stride) {
        float4 v = ((const float4*)W)[i];
        s += (v.x + v.y) + (v.z + v.w);
    }
    #pragma unroll
    for (int off = 32; off > 0; off >>= 1) s += __shfl_down(s, off, 64);
    __shared__ float red[4];
    int t = threadIdx.x;
    if ((t & 63) == 0) red[t >> 6] = s;
    __syncthreads();
    if (t == 0) {
        float bs = red[0] + red[1] + red[2] + red[3];
        atomicAdd(out, (double)bs);
    }
}

// ---------------------------------------------------------------------------
// Kernel 2: quantize W -> bf16 {0,1}
// ---------------------------------------------------------------------------
__global__ void quant_w_kernel(const float* __restrict__ W, ushort_t* __restrict__ Wq,
                               const double* __restrict__ sumw, float inv_n, int n4) {
    float mean = (float)(*sumw) * inv_n;
    int i = blockIdx.x * blockDim.x + threadIdx.x;
    int stride = gridDim.x * blockDim.x;
    for (; i < n4; i += stride) {
        float4 v = ((const float4*)W)[i];
        ushort4 o;
        o.x = (v.x > mean) ? 0x3F80 : 0;
        o.y = (v.y > mean) ? 0x3F80 : 0;
        o.z = (v.z > mean) ? 0x3F80 : 0;
        o.w = (v.w > mean) ? 0x3F80 : 0;
        ((ushort4*)Wq)[i] = o;
    }
}

// ---------------------------------------------------------------------------
// Kernel 3: convert x -> bf16 (round-to-nearest)
// ---------------------------------------------------------------------------
__device__ __forceinline__ ushort_t f2bf(float f) {
    __hip_bfloat16 h = __float2bfloat16(f);
    return *(ushort_t*)&h;
}

__global__ void cvt_x_kernel(const float* __restrict__ x, ushort_t* __restrict__ xb, int n4) {
    int i = blockIdx.x * blockDim.x + threadIdx.x;
    int stride = gridDim.x * blockDim.x;
    for (; i < n4; i += stride) {
        float4 v = ((const float4*)x)[i];
        ushort4 o;
        o.x = f2bf(v.x);
        o.y = f2bf(v.y);
        o.z = f2bf(v.z);
        o.w = f2bf(v.w);
        ((ushort4*)xb)[i] = o;
    }
}

// ---------------------------------------------------------------------------
// Kernel 4: quantize b (single block; n = 4096)
// ---------------------------------------------------------------------------
__global__ void quant_b_kernel(const float* __restrict__ b, float* __restrict__ bq, int n) {
    int t = threadIdx.x;
    float s = 0.f;
    for (int i = t; i < n; i += 256) s += b[i];
    #pragma unroll
    for (int off = 32; off > 0; off >>= 1) s += __shfl_down(s, off, 64);
    __shared__ float red[4];
    if ((t & 63) == 0) red[t >> 6] = s;
    __syncthreads();
    float mean = (red[0] + red[1] + red[2] + red[3]) / (float)n;
    for (int i = t; i < n; i += 256) bq[i] = (b[i] > mean) ? 1.0f : 0.0f;
}

// ---------------------------------------------------------------------------
// Kernel 5: bf16 MFMA GEMM, 256x256 tile, BK=64, 8 waves (2Mx4N), R4's proven
// 4-phase schedule, upgraded to v_mfma_f32_32x32x16_bf16 (measured pipe rate
// 2382 vs 2075 TF for 16x16 -> ~13% less matrix-pipe time; MFMA inst count
// halves). Per wave: 4x2 tiles of 32x32; 8 MFMA per phase.
//   A-frag: lane holds row=l&31, k=(l>>5)*8+e (k-grouping as in the verified
//   16x16x32 case); B-frag symmetric (col=l&31). C/D: col=lane&31,
//   row=(reg&3)+8*(reg>>2)+4*(lane>>5)  [m74/m101 verified].
// Stage order A0',B0',B1',A1'; vmcnt(4) at each phase end (measured free);
// 4 barriers/tile.  C[M,N] = A[M,K] * B[N,K]^T
// LDS swizzle (full-granule): byte ^= ((byte>>3) & 0x70). Involution,
// row-preserving; 8 lanes/16B-granule = wave64 b128 floor (0 conflicts, R3).
// kg selects k-group: addr = (base^xorm) ^ (kg*32) -- valid since base bits
// 5-6 are zero pre-XOR, so +kg*32 == ^kg*32 commutes past the row-XOR.
// ---------------------------------------------------------------------------
#define PRIO1 __builtin_amdgcn_s_setprio(1)
#define PRIO0 __builtin_amdgcn_s_setprio(0)
#define BAR() __builtin_amdgcn_s_barrier()
#define WAITV4() asm volatile("s_waitcnt vmcnt(4)" ::: "memory")
#define WAITV0() asm volatile("s_waitcnt vmcnt(0)" ::: "memory")
#define LGKM0() do { asm volatile("s_waitcnt lgkmcnt(0)" ::: "memory"); \
                     __builtin_amdgcn_sched_barrier(0); } while (0)
#define UNRL _Pragma("unroll")

__global__ __launch_bounds__(512, 2) void gemm_bf16_256(
        const ushort_t* __restrict__ A, const ushort_t* __restrict__ B,
        float* __restrict__ C, int M, int N, int K) {
    __shared__ ushort_t lds8[65536];   // 128 KiB: [buf][A 16K ushorts | B 16K ushorts]
    char* ldsc = (char*)lds8;

    int nbn = N >> 8;
    int nwg = gridDim.x;
    int bid = blockIdx.x;
    int cpx = nwg >> 3;
    int wg = (bid & 7) * cpx + (bid >> 3);   // XCD swizzle (nwg % 8 == 0)
    int tm = wg / nbn, tn = wg % nbn;

    int t = threadIdx.x;
    int w = t >> 6, l = t & 63;
    int wr = w >> 2, wc = w & 3;             // 2 M-waves x 4 N-waves
    int wrOff = wr * 8192;                   // 64 rows * 128 B
    int wcOff = wc * 4096;                   // 32 rows * 128 B

    // 32x32 read-side lane offset: row=l&31 (stride 128B), k-half byte (l>>5)*16,
    // full-granule swizzle folded in. kg k-group applied as ^(kg*32).
    int laneS = (((l & 31) * 128) + ((l >> 5) * 16)) ^ ((l & 7) << 4);

    // stage-side source offsets (inverse swizzle = same involution), 32-bit
    int offA[2][2], offB[2][2];
    UNRL
    for (int c = 0; c < 2; ++c) {
        int o = (t + c * 512) * 16;
        int os = o ^ ((o >> 3) & 0x70);
        int lr = os >> 7;
        int col = (os & 127) >> 1;
        UNRL
        for (int h = 0; h < 2; ++h) {
            offA[c][h] = ((lr >> 6) * 128 + h * 64 + (lr & 63)) * K + col;
            offB[c][h] = ((lr >> 5) * 64 + h * 32 + (lr & 31)) * K + col;
        }
    }

    const ushort_t* srcA = A + (size_t)tm * 256 * K;
    const ushort_t* srcB = B + (size_t)tn * 256 * K;

    f32x16 acc[4][2] = {};                  // [m-tile 0..3][n-tile 0..1]
    bf16x8 af[2][4], bf0[4], bf1[4];        // af[mt][kg]; bfX[kg]

#define STAGE_A(P, H, KIDX) do { \
    GLD16(srcA + (size_t)offA[0][H] + (KIDX), ldsc + (P)*65536 + (H)*16384 + w*1024); \
    GLD16(srcA + (size_t)offA[1][H] + (KIDX), ldsc + (P)*65536 + (H)*16384 + 8192 + w*1024); \
} while (0)
#define STAGE_B(P, H, KIDX) do { \
    GLD16(srcB + (size_t)offB[0][H] + (KIDX), ldsc + (P)*65536 + 32768 + (H)*16384 + w*1024); \
    GLD16(srcB + (size_t)offB[1][H] + (KIDX), ldsc + (P)*65536 + 32768 + (H)*16384 + 8192 + w*1024); \
} while (0)
// A m-half H: 2 M-tiles x 4 k-groups (8 ds_read_b128)
#define LOAD_A32(P, H) do { UNRL for (int mt = 0; mt < 2; ++mt) UNRL for (int kg = 0; kg < 4; ++kg) { \
    af[mt][kg] = *(const bf16x8*)(ldsc + (P)*65536 + (H)*16384 + wrOff + mt*4096 + (laneS ^ (kg*32))); \
} } while (0)
// B n-tile H: 4 k-groups (4 ds_read_b128)
#define LOAD_B32(BF, P, H) do { UNRL for (int kg = 0; kg < 4; ++kg) { \
    BF[kg] = *(const bf16x8*)(ldsc + (P)*65536 + 32768 + (H)*16384 + wcOff + (laneS ^ (kg*32))); \
} } while (0)
// Quadrant = m-half QM x n-tile QN: 2 M-tiles x 4 k-groups = 8 MFMA
#define MFMA_Q(QM, QN, BF) do { UNRL for (int mt = 0; mt < 2; ++mt) UNRL for (int kg = 0; kg < 4; ++kg) { \
    acc[(QM)*2+mt][QN] = __builtin_amdgcn_mfma_f32_32x32x16_bf16(af[mt][kg], BF[kg], acc[(QM)*2+mt][QN], 0, 0, 0); \
} } while (0)

#define TILE(P, PN, KTN) do { \
    LOAD_A32(P, 0); LOAD_B32(bf0, P, 0); STAGE_A(PN, 0, KTN); \
    LGKM0(); PRIO1; MFMA_Q(0, 0, bf0); PRIO0; WAITV4(); BAR(); \
    LOAD_B32(bf1, P, 1);                 STAGE_B(PN, 0, KTN); \
    LGKM0(); PRIO1; MFMA_Q(0, 1, bf1); PRIO0; WAITV4(); BAR(); \
    LOAD_A32(P, 1);                      STAGE_B(PN, 1, KTN); \
    LGKM0(); PRIO1; MFMA_Q(1, 1, bf1); PRIO0; WAITV4(); BAR(); \
                                         STAGE_A(PN, 1, KTN); \
    PRIO1; MFMA_Q(1, 0, bf0); PRIO0; WAITV4(); BAR(); \
} while (0)

    // prologue: stage tile 0 into buf0, drain once (outside main loop)
    STAGE_A(0, 0, 0); STAGE_B(0, 0, 0); STAGE_B(0, 1, 0); STAGE_A(0, 1, 0);
    WAITV0();
    BAR();

    for (int kt = 0; kt < K; kt += 128) {
        int kn1 = kt + 64;
        int kn2 = (kt + 128 < K) ? kt + 128 : 0;   // wrap: redundant, never read
        TILE(0, 1, kn1);
        TILE(1, 0, kn2);
    }

    WAITV0();  // drain trailing stages before epilogue

    // epilogue: 32x32 C/D layout: col = lane&31, row = (r&3)+8*(r>>2)+4*(l>>5)
    int crow0 = tm * 256 + wr * 128 + ((l >> 5) * 4);
    int ccol0 = tn * 256 + wc * 64 + (l & 31);
    UNRL
    for (int am = 0; am < 4; ++am)
        UNRL
        for (int an = 0; an < 2; ++an)
            UNRL
            for (int r = 0; r < 16; ++r) {
                int row = crow0 + am * 32 + (r & 3) + ((r >> 2) * 8);
                C[(size_t)row * N + (ccol0 + an * 32)] = acc[am][an][r];
            }
}

// ---------------------------------------------------------------------------
// Kernel 6: per-row normalize in-place: z = (z + bq - mean) / (sqrt(var_ddof1) + eps)
// ---------------------------------------------------------------------------
__device__ __forceinline__ float block_sum_256(float v, float* red) {
    #pragma unroll
    for (int off = 32; off > 0; off >>= 1) v += __shfl_down(v, off, 64);
    int t = threadIdx.x;
    __syncthreads();
    if ((t & 63) == 0) red[t >> 6] = v;
    __syncthreads();
    return red[0] + red[1] + red[2] + red[3];
}

__global__ void rownorm_kernel(float* __restrict__ z, const float* __restrict__ bq, int N) {
    __shared__ float red[4];
    int row = blockIdx.x;
    float* zr = z + (size_t)row * N;
    int t = threadIdx.x;

    float4 v[4];
    float s = 0.f;
    #pragma unroll
    for (int j = 0; j < 4; ++j) {
        int idx = t + j * 256;
        float4 a = ((const float4*)zr)[idx];
        float4 bb = ((const float4*)bq)[idx];
        a.x += bb.x; a.y += bb.y; a.z += bb.z; a.w += bb.w;
        v[j] = a;
        s += (a.x + a.y) + (a.z + a.w);
    }
    float total = block_sum_256(s, red);
    float mean = total * (1.0f / 4096.0f);

    float q = 0.f;
    #pragma unroll
    for (int j = 0; j < 4; ++j) {
        float dx = v[j].x - mean, dy = v[j].y - mean, dz = v[j].z - mean, dw = v[j].w - mean;
        q += (dx * dx + dy * dy) + (dz * dz + dw * dw);
    }
    float qtot = block_sum_256(q, red);
    float var = qtot * (1.0f / 4095.0f);
    float inv = 1.0f / (sqrtf(var) + 1e-8f);

    #pragma unroll
    for (int j = 0; j < 4; ++j) {
        int idx = t + j * 256;
        float4 o;
        o.x = (v[j].x - mean) * inv;
        o.y = (v[j].y - mean) * inv;
        o.z = (v[j].z - mean) * inv;
        o.w = (v[j].w - mean) * inv;
        ((float4*)zr)[idx] = o;
    }
}

// ---------------------------------------------------------------------------
extern "C" void kernel_launch(void* const* d_in, const int* in_sizes, int n_in,
                              void* d_out, int out_size, void* d_ws, size_t ws_size,
                              hipStream_t stream) {
    const float* x = (const float*)d_in[0];
    const float* W = (const float*)d_in[1];
    const float* b = (const float*)d_in[2];
    float* out = (float*)d_out;

    const int N = in_sizes[2];            // 4096 (OUT)
    const int K = in_sizes[1] / N;        // 4096 (IN)
    const int M = in_sizes[0] / K;        // 8192

    // workspace layout
    char* ws = (char*)d_ws;
    ushort_t* xb = (ushort_t*)ws;                                   // M*K bf16
    ushort_t* wq = (ushort_t*)(ws + (size_t)M * K * 2);             // N*K bf16
    float* bq = (float*)(ws + (size_t)M * K * 2 + (size_t)N * K * 2);  // N fp32
    double* sumw = (double*)(ws + (size_t)M * K * 2 + (size_t)N * K * 2 + (size_t)N * 4);

    hipMemsetAsync(sumw, 0, sizeof(double), stream);
    sum_w_kernel<<<1024, 256, 0, stream>>>(W, sumw, N * K / 4);
    quant_w_kernel<<<2048, 256, 0, stream>>>(W, wq, sumw, 1.0f / (float)((size_t)N * K), N * K / 4);
    cvt_x_kernel<<<2048, 256, 0, stream>>>(x, xb, M * K / 4);
    quant_b_kernel<<<1, 256, 0, stream>>>(b, bq, N);

    int grid = (M / 256) * (N / 256);
    gemm_bf16_256<<<grid, 512, 0, stream>>>(xb, wq, out, M, N, K);

    rownorm_kernel<<<M, 256, 0, stream>>>(out, bq, N);
}

// Round 11
// 333.590 us; speedup vs baseline: 1.5219x; 1.0838x over previous
//
#include <hip/hip_runtime.h>
#include <hip/hip_bf16.h>

typedef unsigned short ushort_t;
typedef float f32x4 __attribute__((ext_vector_type(4)));
typedef __bf16 bf16x8 __attribute__((ext_vector_type(8)));

typedef const __attribute__((address_space(1))) void* gptr_t;
typedef __attribute__((address_space(3))) void* sptr_t;

#define GLD16(g, l) __builtin_amdgcn_global_load_lds((gptr_t)(g), (sptr_t)(l), 16, 0, 0)

// ---------------------------------------------------------------------------
// Kernel 1: global sum of W (fp32 partials, double atomic) -> ws scalar
// ---------------------------------------------------------------------------
__global__ void sum_w_kernel(const float* __restrict__ W, double* __restrict__ out, int n4) {
    int i = blockIdx.x * blockDim.x + threadIdx.x;
    int stride = gridDim.x * blockDim.x;
    float s = 0.f;
    for (; i < n4; i += stride) {
        float4 v = ((const float4*)W)[i];
        s += (v.x + v.y) + (v.z + v.w);
    }
    #pragma unroll
    for (int off = 32; off > 0; off >>= 1) s += __shfl_down(s, off, 64);
    __shared__ float red[4];
    int t = threadIdx.x;
    if ((t & 63) == 0) red[t >> 6] = s;
    __syncthreads();
    if (t == 0) {
        float bs = red[0] + red[1] + red[2] + red[3];
        atomicAdd(out, (double)bs);
    }
}

// ---------------------------------------------------------------------------
// Kernel 2: quantize W -> bf16 {0,1}
// ---------------------------------------------------------------------------
__global__ void quant_w_kernel(const float* __restrict__ W, ushort_t* __restrict__ Wq,
                               const double* __restrict__ sumw, float inv_n, int n4) {
    float mean = (float)(*sumw) * inv_n;
    int i = blockIdx.x * blockDim.x + threadIdx.x;
    int stride = gridDim.x * blockDim.x;
    for (; i < n4; i += stride) {
        float4 v = ((const float4*)W)[i];
        ushort4 o;
        o.x = (v.x > mean) ? 0x3F80 : 0;
        o.y = (v.y > mean) ? 0x3F80 : 0;
        o.z = (v.z > mean) ? 0x3F80 : 0;
        o.w = (v.w > mean) ? 0x3F80 : 0;
        ((ushort4*)Wq)[i] = o;
    }
}

// ---------------------------------------------------------------------------
// Kernel 3: convert x -> bf16 (round-to-nearest)
// ---------------------------------------------------------------------------
__device__ __forceinline__ ushort_t f2bf(float f) {
    __hip_bfloat16 h = __float2bfloat16(f);
    return *(ushort_t*)&h;
}

__global__ void cvt_x_kernel(const float* __restrict__ x, ushort_t* __restrict__ xb, int n4) {
    int i = blockIdx.x * blockDim.x + threadIdx.x;
    int stride = gridDim.x * blockDim.x;
    for (; i < n4; i += stride) {
        float4 v = ((const float4*)x)[i];
        ushort4 o;
        o.x = f2bf(v.x);
        o.y = f2bf(v.y);
        o.z = f2bf(v.z);
        o.w = f2bf(v.w);
        ((ushort4*)xb)[i] = o;
    }
}

// ---------------------------------------------------------------------------
// Kernel 4: quantize b (single block; n = 4096)
// ---------------------------------------------------------------------------
__global__ void quant_b_kernel(const float* __restrict__ b, float* __restrict__ bq, int n) {
    int t = threadIdx.x;
    float s = 0.f;
    for (int i = t; i < n; i += 256) s += b[i];
    #pragma unroll
    for (int off = 32; off > 0; off >>= 1) s += __shfl_down(s, off, 64);
    __shared__ float red[4];
    if ((t & 63) == 0) red[t >> 6] = s;
    __syncthreads();
    float mean = (red[0] + red[1] + red[2] + red[3]) / (float)n;
    for (int i = t; i < n; i += 256) bq[i] = (b[i] > mean) ? 1.0f : 0.0f;
}

// ---------------------------------------------------------------------------
// Kernel 5: bf16 MFMA GEMM, 256x256 tile, BK=64, 8 waves (2Mx4N), R4's proven
// 4-phase schedule (best measured: 226us, 0 conflicts), 16x16x32 MFMA.
// Stage order A0',B0',B1',A1'; vmcnt(4) at each phase end; 4 barriers/tile.
//   C[M,N] = A[M,K] * B[N,K]^T
// LDS swizzle (full-granule): byte ^= ((byte>>3) & 0x70). Involution,
// row-preserving; 8 lanes/16B-granule = wave64 b128 floor (0 conflicts, R3).
// NEW (R11): coalesced epilogue. Old epilogue = scalar stores in 64B segments
// (4 row-groups x 16 cols per instr). Now: bounce acc through LDS (4 chunks
// of 32 rows x 64 cols per wave, stride 68 floats = 272B, 16B-aligned) and
// store f32x4 per lane -> four 256B contiguous segments per instruction.
// ---------------------------------------------------------------------------
#define PRIO1 __builtin_amdgcn_s_setprio(1)
#define PRIO0 __builtin_amdgcn_s_setprio(0)
#define BAR() __builtin_amdgcn_s_barrier()
#define WAITV4() asm volatile("s_waitcnt vmcnt(4)" ::: "memory")
#define WAITV0() asm volatile("s_waitcnt vmcnt(0)" ::: "memory")
#define UNRL _Pragma("unroll")

__global__ __launch_bounds__(512, 2) void gemm_bf16_256(
        const ushort_t* __restrict__ A, const ushort_t* __restrict__ B,
        float* __restrict__ C, int M, int N, int K) {
    __shared__ ushort_t lds8[65536];   // 128 KiB: [buf][A 16K ushorts | B 16K ushorts]
    char* ldsc = (char*)lds8;
    float* ldsf = (float*)lds8;        // epilogue bounce reuses the same LDS

    int nbn = N >> 8;
    int nwg = gridDim.x;
    int bid = blockIdx.x;
    int cpx = nwg >> 3;
    int wg = (bid & 7) * cpx + (bid >> 3);   // XCD swizzle (nwg % 8 == 0)
    int tm = wg / nbn, tn = wg % nbn;

    int t = threadIdx.x;
    int w = t >> 6, l = t & 63;
    int wr = w >> 2, wc = w & 3;             // 2 M-waves x 4 N-waves
    int wrOff = wr * 8192;                   // 64 rows * 128 B
    int wcOff = wc * 4096;                   // 32 rows * 128 B

    // read-side lane offsets, full-granule swizzle folded in
    int baseL = ((l & 15) * 128) + ((l >> 4) * 16);
    int laneA0 = baseL ^ ((l & 7) << 4);     // K elems 0..31
    int laneA1 = laneA0 ^ 64;                // K elems 32..63 (bit6 flip pre-swz)

    // stage-side source offsets (inverse swizzle = same involution), 32-bit
    int offA[2][2], offB[2][2];
    UNRL
    for (int c = 0; c < 2; ++c) {
        int o = (t + c * 512) * 16;
        int os = o ^ ((o >> 3) & 0x70);
        int lr = os >> 7;
        int col = (os & 127) >> 1;
        UNRL
        for (int h = 0; h < 2; ++h) {
            offA[c][h] = ((lr >> 6) * 128 + h * 64 + (lr & 63)) * K + col;
            offB[c][h] = ((lr >> 5) * 64 + h * 32 + (lr & 31)) * K + col;
        }
    }

    const ushort_t* srcA = A + (size_t)tm * 256 * K;
    const ushort_t* srcB = B + (size_t)tn * 256 * K;

    f32x4 acc[8][4] = {};
    bf16x8 af[4][2], bf0[2][2], bf1[2][2];

#define STAGE_A(P, H, KIDX) do { \
    GLD16(srcA + (size_t)offA[0][H] + (KIDX), ldsc + (P)*65536 + (H)*16384 + w*1024); \
    GLD16(srcA + (size_t)offA[1][H] + (KIDX), ldsc + (P)*65536 + (H)*16384 + 8192 + w*1024); \
} while (0)
#define STAGE_B(P, H, KIDX) do { \
    GLD16(srcB + (size_t)offB[0][H] + (KIDX), ldsc + (P)*65536 + 32768 + (H)*16384 + w*1024); \
    GLD16(srcB + (size_t)offB[1][H] + (KIDX), ldsc + (P)*65536 + 32768 + (H)*16384 + 8192 + w*1024); \
} while (0)
#define LOAD_AF(P, H) do { UNRL for (int f = 0; f < 4; ++f) { \
    af[f][0] = *(const bf16x8*)(ldsc + (P)*65536 + (H)*16384 + wrOff + f*2048 + laneA0); \
    af[f][1] = *(const bf16x8*)(ldsc + (P)*65536 + (H)*16384 + wrOff + f*2048 + laneA1); \
} } while (0)
#define LOAD_BF(BF, P, H) do { UNRL for (int e = 0; e < 2; ++e) { \
    BF[e][0] = *(const bf16x8*)(ldsc + (P)*65536 + 32768 + (H)*16384 + wcOff + e*2048 + laneA0); \
    BF[e][1] = *(const bf16x8*)(ldsc + (P)*65536 + 32768 + (H)*16384 + wcOff + e*2048 + laneA1); \
} } while (0)
#define MFMA_Q(QM, QN, BF) do { UNRL for (int f = 0; f < 4; ++f) UNRL for (int e = 0; e < 2; ++e) { \
    acc[(QM)*4+f][(QN)*2+e] = __builtin_amdgcn_mfma_f32_16x16x32_bf16(af[f][0], BF[e][0], acc[(QM)*4+f][(QN)*2+e], 0, 0, 0); \
    acc[(QM)*4+f][(QN)*2+e] = __builtin_amdgcn_mfma_f32_16x16x32_bf16(af[f][1], BF[e][1], acc[(QM)*4+f][(QN)*2+e], 0, 0, 0); \
} } while (0)

#define TILE(P, PN, KTN) do { \
    LOAD_AF(P, 0); LOAD_BF(bf0, P, 0); STAGE_A(PN, 0, KTN); \
    PRIO1; MFMA_Q(0, 0, bf0); PRIO0; WAITV4(); BAR(); \
    LOAD_BF(bf1, P, 1);                STAGE_B(PN, 0, KTN); \
    PRIO1; MFMA_Q(0, 1, bf1); PRIO0; WAITV4(); BAR(); \
    LOAD_AF(P, 1);                     STAGE_B(PN, 1, KTN); \
    PRIO1; MFMA_Q(1, 1, bf1); PRIO0; WAITV4(); BAR(); \
                                       STAGE_A(PN, 1, KTN); \
    PRIO1; MFMA_Q(1, 0, bf0); PRIO0; WAITV4(); BAR(); \
} while (0)

    // prologue: stage tile 0 into buf0, drain once (outside main loop)
    STAGE_A(0, 0, 0); STAGE_B(0, 0, 0); STAGE_B(0, 1, 0); STAGE_A(0, 1, 0);
    WAITV0();
    BAR();

    for (int kt = 0; kt < K; kt += 128) {
        int kn1 = kt + 64;
        int kn2 = (kt + 128 < K) ? kt + 128 : 0;   // wrap: redundant, never read
        TILE(0, 1, kn1);
        TILE(1, 0, kn2);
    }

    WAITV0();  // drain trailing stages (incl. wrapped GLD16 into the buffers)
    BAR();     // all waves' LDS writes retired before bounce reuse

    // -----------------------------------------------------------------------
    // Coalesced epilogue. Frag layout: value (fm,fn,r) at
    //   row = wr*128 + fm*16 + (l>>4)*4 + r,  col = wc*64 + fn*16 + (l&15).
    // 4 chunks of 2 fm-frags (32 rows x 64 cols per wave). Per-wave LDS
    // region: 32 rows x 68 floats (stride 272B, 16B-aligned), base w*2176.
    // Store: lane l writes f32x4 at row rr*4+(l>>4), cols (l&15)*4..+3 ->
    // per instr: 4 segments x 256B contiguous.
    // -----------------------------------------------------------------------
    {
        int crowW = tm * 256 + wr * 128;       // wave row base
        int ccolW = tn * 256 + wc * 64;        // wave col base
        int lq = l >> 4, lc = l & 15;
        UNRL
        for (int c = 0; c < 4; ++c) {
            UNRL
            for (int fi = 0; fi < 2; ++fi) {
                int fm = c * 2 + fi;
                UNRL
                for (int fn = 0; fn < 4; ++fn)
                    UNRL
                    for (int r = 0; r < 4; ++r)
                        ldsf[w * 2176 + (fi * 16 + lq * 4 + r) * 68 + fn * 16 + lc]
                            = acc[fm][fn][r];
            }
            BAR();
            UNRL
            for (int rr = 0; rr < 8; ++rr) {
                f32x4 v = *(const f32x4*)&ldsf[w * 2176 + (rr * 4 + lq) * 68 + lc * 4];
                *(f32x4*)&C[(size_t)(crowW + c * 32 + rr * 4 + lq) * N + (ccolW + lc * 4)] = v;
            }
            BAR();   // region reused by next chunk
        }
    }
}

// ---------------------------------------------------------------------------
// Kernel 6: per-row normalize in-place: z = (z + bq - mean) / (sqrt(var_ddof1) + eps)
// ---------------------------------------------------------------------------
__device__ __forceinline__ float block_sum_256(float v, float* red) {
    #pragma unroll
    for (int off = 32; off > 0; off >>= 1) v += __shfl_down(v, off, 64);
    int t = threadIdx.x;
    __syncthreads();
    if ((t & 63) == 0) red[t >> 6] = v;
    __syncthreads();
    return red[0] + red[1] + red[2] + red[3];
}

__global__ void rownorm_kernel(float* __restrict__ z, const float* __restrict__ bq, int N) {
    __shared__ float red[4];
    int row = blockIdx.x;
    float* zr = z + (size_t)row * N;
    int t = threadIdx.x;

    float4 v[4];
    float s = 0.f;
    #pragma unroll
    for (int j = 0; j < 4; ++j) {
        int idx = t + j * 256;
        float4 a = ((const float4*)zr)[idx];
        float4 bb = ((const float4*)bq)[idx];
        a.x += bb.x; a.y += bb.y; a.z += bb.z; a.w += bb.w;
        v[j] = a;
        s += (a.x + a.y) + (a.z + a.w);
    }
    float total = block_sum_256(s, red);
    float mean = total * (1.0f / 4096.0f);

    float q = 0.f;
    #pragma unroll
    for (int j = 0; j < 4; ++j) {
        float dx = v[j].x - mean, dy = v[j].y - mean, dz = v[j].z - mean, dw = v[j].w - mean;
        q += (dx * dx + dy * dy) + (dz * dz + dw * dw);
    }
    float qtot = block_sum_256(q, red);
    float var = qtot * (1.0f / 4095.0f);
    float inv = 1.0f / (sqrtf(var) + 1e-8f);

    #pragma unroll
    for (int j = 0; j < 4; ++j) {
        int idx = t + j * 256;
        float4 o;
        o.x = (v[j].x - mean) * inv;
        o.y = (v[j].y - mean) * inv;
        o.z = (v[j].z - mean) * inv;
        o.w = (v[j].w - mean) * inv;
        ((float4*)zr)[idx] = o;
    }
}

// ---------------------------------------------------------------------------
extern "C" void kernel_launch(void* const* d_in, const int* in_sizes, int n_in,
                              void* d_out, int out_size, void* d_ws, size_t ws_size,
                              hipStream_t stream) {
    const float* x = (const float*)d_in[0];
    const float* W = (const float*)d_in[1];
    const float* b = (const float*)d_in[2];
    float* out = (float*)d_out;

    const int N = in_sizes[2];            // 4096 (OUT)
    const int K = in_sizes[1] / N;        // 4096 (IN)
    const int M = in_sizes[0] / K;        // 8192

    // workspace layout
    char* ws = (char*)d_ws;
    ushort_t* xb = (ushort_t*)ws;                                   // M*K bf16
    ushort_t* wq = (ushort_t*)(ws + (size_t)M * K * 2);             // N*K bf16
    float* bq = (float*)(ws + (size_t)M * K * 2 + (size_t)N * K * 2);  // N fp32
    double* sumw = (double*)(ws + (size_t)M * K * 2 + (size_t)N * K * 2 + (size_t)N * 4);

    hipMemsetAsync(sumw, 0, sizeof(double), stream);
    sum_w_kernel<<<1024, 256, 0, stream>>>(W, sumw, N * K / 4);
    quant_w_kernel<<<2048, 256, 0, stream>>>(W, wq, sumw, 1.0f / (float)((size_t)N * K), N * K / 4);
    cvt_x_kernel<<<2048, 256, 0, stream>>>(x, xb, M * K / 4);
    quant_b_kernel<<<1, 256, 0, stream>>>(b, bq, N);

    int grid = (M / 256) * (N / 256);
    gemm_bf16_256<<<grid, 512, 0, stream>>>(xb, wq, out, M, N, K);

    rownorm_kernel<<<M, 256, 0, stream>>>(out, bq, N);
}

// Round 12
// 235.047 us; speedup vs baseline: 2.1600x; 1.4192x over previous
//
#include <hip/hip_runtime.h>
#include <hip/hip_bf16.h>

typedef signed char i8_t;
typedef int i32x4 __attribute__((ext_vector_type(4)));
typedef float f32x4 __attribute__((ext_vector_type(4)));

typedef const __attribute__((address_space(1))) void* gptr_t;
typedef __attribute__((address_space(3))) void* sptr_t;

#define GLD16(g, l) __builtin_amdgcn_global_load_lds((gptr_t)(g), (sptr_t)(l), 16, 0, 0)

// ---------------------------------------------------------------------------
// Kernel 1: global sum of W (fp32 partials, double atomic) -> ws scalar
// ---------------------------------------------------------------------------
__global__ void sum_w_kernel(const float* __restrict__ W, double* __restrict__ out, int n4) {
    int i = blockIdx.x * blockDim.x + threadIdx.x;
    int stride = gridDim.x * blockDim.x;
    float s = 0.f;
    for (; i < n4; i += stride) {
        float4 v = ((const float4*)W)[i];
        s += (v.x + v.y) + (v.z + v.w);
    }
    #pragma unroll
    for (int off = 32; off > 0; off >>= 1) s += __shfl_down(s, off, 64);
    __shared__ float red[4];
    int t = threadIdx.x;
    if ((t & 63) == 0) red[t >> 6] = s;
    __syncthreads();
    if (t == 0) {
        float bs = red[0] + red[1] + red[2] + red[3];
        atomicAdd(out, (double)bs);
    }
}

// ---------------------------------------------------------------------------
// Kernel 2: quantize W -> i8 {0,1}
// ---------------------------------------------------------------------------
__global__ void quant_w_kernel(const float* __restrict__ W, i8_t* __restrict__ Wq,
                               const double* __restrict__ sumw, float inv_n, int n4) {
    float mean = (float)(*sumw) * inv_n;
    int i = blockIdx.x * blockDim.x + threadIdx.x;
    int stride = gridDim.x * blockDim.x;
    for (; i < n4; i += stride) {
        float4 v = ((const float4*)W)[i];
        char4 o;
        o.x = (v.x > mean) ? 1 : 0;
        o.y = (v.y > mean) ? 1 : 0;
        o.z = (v.z > mean) ? 1 : 0;
        o.w = (v.w > mean) ? 1 : 0;
        ((char4*)Wq)[i] = o;
    }
}

// ---------------------------------------------------------------------------
// Kernel 3: per-row symmetric int8 quantization of x (one block per row).
// s_row = absmax/127; xq = rint(x/s) clamped; scale[row] = s_row.
// Normalization is affine-invariant per row, so s_row is re-applied in
// rownorm (a = z*s + bq) and the GEMM runs purely in int8/int32.
// ---------------------------------------------------------------------------
__global__ void quant_x_kernel(const float* __restrict__ x, i8_t* __restrict__ xq,
                               float* __restrict__ scale, int K) {
    __shared__ float red[4];
    int row = blockIdx.x;
    int t = threadIdx.x;
    const float4* xr = (const float4*)(x + (size_t)row * K);

    float4 v[4];
    float am = 0.f;
    #pragma unroll
    for (int j = 0; j < 4; ++j) {
        v[j] = xr[t + j * 256];
        am = fmaxf(am, fmaxf(fmaxf(fabsf(v[j].x), fabsf(v[j].y)),
                             fmaxf(fabsf(v[j].z), fabsf(v[j].w))));
    }
    #pragma unroll
    for (int off = 32; off > 0; off >>= 1) am = fmaxf(am, __shfl_down(am, off, 64));
    if ((t & 63) == 0) red[t >> 6] = am;
    __syncthreads();
    float amax = fmaxf(fmaxf(red[0], red[1]), fmaxf(red[2], red[3]));
    amax = fmaxf(amax, 1e-20f);
    float s = amax * (1.0f / 127.0f);
    float inv = 127.0f / amax;
    if (t == 0) scale[row] = s;

    char4* oq = (char4*)(xq + (size_t)row * K);
    #pragma unroll
    for (int j = 0; j < 4; ++j) {
        char4 o;
        o.x = (i8_t)(int)rintf(fminf(fmaxf(v[j].x * inv, -127.f), 127.f));
        o.y = (i8_t)(int)rintf(fminf(fmaxf(v[j].y * inv, -127.f), 127.f));
        o.z = (i8_t)(int)rintf(fminf(fmaxf(v[j].z * inv, -127.f), 127.f));
        o.w = (i8_t)(int)rintf(fminf(fmaxf(v[j].w * inv, -127.f), 127.f));
        oq[t + j * 256] = o;
    }
}

// ---------------------------------------------------------------------------
// Kernel 4: quantize b (single block; n = 4096)
// ---------------------------------------------------------------------------
__global__ void quant_b_kernel(const float* __restrict__ b, float* __restrict__ bq, int n) {
    int t = threadIdx.x;
    float s = 0.f;
    for (int i = t; i < n; i += 256) s += b[i];
    #pragma unroll
    for (int off = 32; off > 0; off >>= 1) s += __shfl_down(s, off, 64);
    __shared__ float red[4];
    if ((t & 63) == 0) red[t >> 6] = s;
    __syncthreads();
    float mean = (red[0] + red[1] + red[2] + red[3]) / (float)n;
    for (int i = t; i < n; i += 256) bq[i] = (b[i] > mean) ? 1.0f : 0.0f;
}

// ---------------------------------------------------------------------------
// Kernel 5: INT8 MFMA GEMM, 256x256 tile, BK=128 (i8 rows = 128 B, byte-
// identical LDS layout/swizzle/stage-offsets to the verified bf16 R4 kernel;
// 0 bank conflicts). R4's proven 4-phase schedule: stage order A0',B0',B1',
// A1'; vmcnt(4) per phase end; 4 barriers/tile.
//   C[M,N] = (float)( A_i8[M,K] * B_i8[N,K]^T )   (scale re-applied in rownorm)
// MFMA: v_mfma_i32_16x16x64_i8 (1.9x bf16 rate, m16) — frag: lane group
// g=(l>>4) holds k=g*16+[0,16) bytes; laneA1=^64 covers k 64..127.
// LDS swizzle (full-granule): byte ^= ((byte>>3) & 0x70).
// Epilogue: i32->float, coalesced via LDS bounce (f32x4 stores, 256B segs).
// ---------------------------------------------------------------------------
#define PRIO1 __builtin_amdgcn_s_setprio(1)
#define PRIO0 __builtin_amdgcn_s_setprio(0)
#define BAR() __builtin_amdgcn_s_barrier()
#define WAITV4() asm volatile("s_waitcnt vmcnt(4)" ::: "memory")
#define WAITV0() asm volatile("s_waitcnt vmcnt(0)" ::: "memory")
#define UNRL _Pragma("unroll")

__global__ __launch_bounds__(512, 2) void gemm_i8_256(
        const i8_t* __restrict__ A, const i8_t* __restrict__ B,
        float* __restrict__ C, int M, int N, int K) {
    __shared__ int lds32[32768];       // 128 KiB: [buf][A 32K i8 | B 32K i8]
    char* ldsc = (char*)lds32;
    float* ldsf = (float*)lds32;       // epilogue bounce reuses the same LDS

    int nbn = N >> 8;
    int nwg = gridDim.x;
    int bid = blockIdx.x;
    int cpx = nwg >> 3;
    int wg = (bid & 7) * cpx + (bid >> 3);   // XCD swizzle (nwg % 8 == 0)
    int tm = wg / nbn, tn = wg % nbn;

    int t = threadIdx.x;
    int w = t >> 6, l = t & 63;
    int wr = w >> 2, wc = w & 3;             // 2 M-waves x 4 N-waves
    int wrOff = wr * 8192;                   // 64 rows * 128 B
    int wcOff = wc * 4096;                   // 32 rows * 128 B

    // read-side lane offsets (bytes), full-granule swizzle folded in
    int baseL = ((l & 15) * 128) + ((l >> 4) * 16);
    int laneA0 = baseL ^ ((l & 7) << 4);     // K bytes 0..63
    int laneA1 = laneA0 ^ 64;                // K bytes 64..127

    // stage-side source offsets (i8 elems == bytes), inverse swizzle
    int offA[2][2], offB[2][2];
    UNRL
    for (int c = 0; c < 2; ++c) {
        int o = (t + c * 512) * 16;
        int os = o ^ ((o >> 3) & 0x70);
        int lr = os >> 7;
        int col = os & 127;
        UNRL
        for (int h = 0; h < 2; ++h) {
            offA[c][h] = ((lr >> 6) * 128 + h * 64 + (lr & 63)) * K + col;
            offB[c][h] = ((lr >> 5) * 64 + h * 32 + (lr & 31)) * K + col;
        }
    }

    const i8_t* srcA = A + (size_t)tm * 256 * K;
    const i8_t* srcB = B + (size_t)tn * 256 * K;

    i32x4 acc[8][4] = {};
    i32x4 af[4][2], bf0[2][2], bf1[2][2];

#define STAGE_A(P, H, KIDX) do { \
    GLD16(srcA + (size_t)offA[0][H] + (KIDX), ldsc + (P)*65536 + (H)*16384 + w*1024); \
    GLD16(srcA + (size_t)offA[1][H] + (KIDX), ldsc + (P)*65536 + (H)*16384 + 8192 + w*1024); \
} while (0)
#define STAGE_B(P, H, KIDX) do { \
    GLD16(srcB + (size_t)offB[0][H] + (KIDX), ldsc + (P)*65536 + 32768 + (H)*16384 + w*1024); \
    GLD16(srcB + (size_t)offB[1][H] + (KIDX), ldsc + (P)*65536 + 32768 + (H)*16384 + 8192 + w*1024); \
} while (0)
#define LOAD_AF(P, H) do { UNRL for (int f = 0; f < 4; ++f) { \
    af[f][0] = *(const i32x4*)(ldsc + (P)*65536 + (H)*16384 + wrOff + f*2048 + laneA0); \
    af[f][1] = *(const i32x4*)(ldsc + (P)*65536 + (H)*16384 + wrOff + f*2048 + laneA1); \
} } while (0)
#define LOAD_BF(BF, P, H) do { UNRL for (int e = 0; e < 2; ++e) { \
    BF[e][0] = *(const i32x4*)(ldsc + (P)*65536 + 32768 + (H)*16384 + wcOff + e*2048 + laneA0); \
    BF[e][1] = *(const i32x4*)(ldsc + (P)*65536 + 32768 + (H)*16384 + wcOff + e*2048 + laneA1); \
} } while (0)
#define MFMA_Q(QM, QN, BF) do { UNRL for (int f = 0; f < 4; ++f) UNRL for (int e = 0; e < 2; ++e) { \
    acc[(QM)*4+f][(QN)*2+e] = __builtin_amdgcn_mfma_i32_16x16x64_i8(af[f][0], BF[e][0], acc[(QM)*4+f][(QN)*2+e], 0, 0, 0); \
    acc[(QM)*4+f][(QN)*2+e] = __builtin_amdgcn_mfma_i32_16x16x64_i8(af[f][1], BF[e][1], acc[(QM)*4+f][(QN)*2+e], 0, 0, 0); \
} } while (0)

#define TILE(P, PN, KTN) do { \
    LOAD_AF(P, 0); LOAD_BF(bf0, P, 0); STAGE_A(PN, 0, KTN); \
    PRIO1; MFMA_Q(0, 0, bf0); PRIO0; WAITV4(); BAR(); \
    LOAD_BF(bf1, P, 1);                STAGE_B(PN, 0, KTN); \
    PRIO1; MFMA_Q(0, 1, bf1); PRIO0; WAITV4(); BAR(); \
    LOAD_AF(P, 1);                     STAGE_B(PN, 1, KTN); \
    PRIO1; MFMA_Q(1, 1, bf1); PRIO0; WAITV4(); BAR(); \
                                       STAGE_A(PN, 1, KTN); \
    PRIO1; MFMA_Q(1, 0, bf0); PRIO0; WAITV4(); BAR(); \
} while (0)

    // prologue: stage tile 0 (K 0..127) into buf0, drain once
    STAGE_A(0, 0, 0); STAGE_B(0, 0, 0); STAGE_B(0, 1, 0); STAGE_A(0, 1, 0);
    WAITV0();
    BAR();

    for (int kt = 0; kt < K; kt += 256) {
        int kn1 = kt + 128;
        int kn2 = (kt + 256 < K) ? kt + 256 : 0;   // wrap: redundant, never read
        TILE(0, 1, kn1);
        TILE(1, 0, kn2);
    }

    WAITV0();  // drain trailing stages (incl. wrapped GLD16 into the buffers)
    BAR();     // all waves' LDS writes retired before bounce reuse

    // Coalesced epilogue (i32 -> float). Frag layout: (fm,fn,r) at
    // row = wr*128 + fm*16 + (l>>4)*4 + r, col = wc*64 + fn*16 + (l&15).
    {
        int crowW = tm * 256 + wr * 128;
        int ccolW = tn * 256 + wc * 64;
        int lq = l >> 4, lc = l & 15;
        UNRL
        for (int c = 0; c < 4; ++c) {
            UNRL
            for (int fi = 0; fi < 2; ++fi) {
                int fm = c * 2 + fi;
                UNRL
                for (int fn = 0; fn < 4; ++fn)
                    UNRL
                    for (int r = 0; r < 4; ++r)
                        ldsf[w * 2176 + (fi * 16 + lq * 4 + r) * 68 + fn * 16 + lc]
                            = (float)acc[fm][fn][r];
            }
            BAR();
            UNRL
            for (int rr = 0; rr < 8; ++rr) {
                f32x4 v = *(const f32x4*)&ldsf[w * 2176 + (rr * 4 + lq) * 68 + lc * 4];
                *(f32x4*)&C[(size_t)(crowW + c * 32 + rr * 4 + lq) * N + (ccolW + lc * 4)] = v;
            }
            BAR();
        }
    }
}

// ---------------------------------------------------------------------------
// Kernel 6: per-row normalize in-place with row scale:
//   a = z*s_row + bq;  out = (a - mean) / (sqrt(var_ddof1) + eps)
// ---------------------------------------------------------------------------
__device__ __forceinline__ float block_sum_256(float v, float* red) {
    #pragma unroll
    for (int off = 32; off > 0; off >>= 1) v += __shfl_down(v, off, 64);
    int t = threadIdx.x;
    __syncthreads();
    if ((t & 63) == 0) red[t >> 6] = v;
    __syncthreads();
    return red[0] + red[1] + red[2] + red[3];
}

__global__ void rownorm_kernel(float* __restrict__ z, const float* __restrict__ bq,
                               const float* __restrict__ scale, int N) {
    __shared__ float red[4];
    int row = blockIdx.x;
    float* zr = z + (size_t)row * N;
    float srow = scale[row];
    int t = threadIdx.x;

    float4 v[4];
    float s = 0.f;
    #pragma unroll
    for (int j = 0; j < 4; ++j) {
        int idx = t + j * 256;
        float4 a = ((const float4*)zr)[idx];
        float4 bb = ((const float4*)bq)[idx];
        a.x = a.x * srow + bb.x; a.y = a.y * srow + bb.y;
        a.z = a.z * srow + bb.z; a.w = a.w * srow + bb.w;
        v[j] = a;
        s += (a.x + a.y) + (a.z + a.w);
    }
    float total = block_sum_256(s, red);
    float mean = total * (1.0f / 4096.0f);

    float q = 0.f;
    #pragma unroll
    for (int j = 0; j < 4; ++j) {
        float dx = v[j].x - mean, dy = v[j].y - mean, dz = v[j].z - mean, dw = v[j].w - mean;
        q += (dx * dx + dy * dy) + (dz * dz + dw * dw);
    }
    float qtot = block_sum_256(q, red);
    float var = qtot * (1.0f / 4095.0f);
    float inv = 1.0f / (sqrtf(var) + 1e-8f);

    #pragma unroll
    for (int j = 0; j < 4; ++j) {
        int idx = t + j * 256;
        float4 o;
        o.x = (v[j].x - mean) * inv;
        o.y = (v[j].y - mean) * inv;
        o.z = (v[j].z - mean) * inv;
        o.w = (v[j].w - mean) * inv;
        ((float4*)zr)[idx] = o;
    }
}

// ---------------------------------------------------------------------------
extern "C" void kernel_launch(void* const* d_in, const int* in_sizes, int n_in,
                              void* d_out, int out_size, void* d_ws, size_t ws_size,
                              hipStream_t stream) {
    const float* x = (const float*)d_in[0];
    const float* W = (const float*)d_in[1];
    const float* b = (const float*)d_in[2];
    float* out = (float*)d_out;

    const int N = in_sizes[2];            // 4096 (OUT)
    const int K = in_sizes[1] / N;        // 4096 (IN)
    const int M = in_sizes[0] / K;        // 8192

    // workspace layout
    char* ws = (char*)d_ws;
    i8_t* xq = (i8_t*)ws;                                           // M*K i8
    i8_t* wq = (i8_t*)(ws + (size_t)M * K);                         // N*K i8
    float* scales = (float*)(ws + (size_t)M * K + (size_t)N * K);   // M fp32
    float* bq = (float*)(ws + (size_t)M * K + (size_t)N * K + (size_t)M * 4);  // N fp32
    double* sumw = (double*)(ws + (size_t)M * K + (size_t)N * K + (size_t)M * 4 + (size_t)N * 4);

    hipMemsetAsync(sumw, 0, sizeof(double), stream);
    sum_w_kernel<<<1024, 256, 0, stream>>>(W, sumw, N * K / 4);
    quant_w_kernel<<<2048, 256, 0, stream>>>(W, wq, sumw, 1.0f / (float)((size_t)N * K), N * K / 4);
    quant_x_kernel<<<M, 256, 0, stream>>>(x, xq, scales, K);
    quant_b_kernel<<<1, 256, 0, stream>>>(b, bq, N);

    int grid = (M / 256) * (N / 256);
    gemm_i8_256<<<grid, 512, 0, stream>>>(xq, wq, out, M, N, K);

    rownorm_kernel<<<M, 256, 0, stream>>>(out, bq, scales, N);
}